// Round 12
// baseline (195.921 us; speedup 1.0000x reference)
//
#include <hip/hip_runtime.h>

#define VOCAB 50000
#define VDIM 256
#define TOPICS 512
#define VT 32
#define NBLK 1563    // ceil(VOCAB/32)  (s kernel)
#define NBLK16 3125  // VOCAB/16        (mu kernel, exact)

typedef unsigned int uint;
typedef unsigned short ushort;
using short8 = __attribute__((ext_vector_type(8))) short;
using f32x4  = __attribute__((ext_vector_type(4))) float;

__device__ __forceinline__ ushort bf16_rne(float f) {
  uint u = __float_as_uint(f);
  u += 0x7FFFu + ((u >> 16) & 1u);
  return (ushort)(u >> 16);
}
__device__ __forceinline__ float bf16f(ushort h) {
  return __uint_as_float(((uint)h) << 16);
}

// ---------------------------------------------------------------------------
// Precompute, single-plane bf16 fragment-major packing (R11 layout):
//   tBp[tile=t>>4][ks=d>>5][lane=(t&15)|(((d>>3)&3)<<4)][e=d&7]   (256 KB)
//   Atp[dtile=d>>4][ks=t>>5][lane=(d&15)|(((t>>3)&3)<<4)][e=t&7]  (256 KB)
// ---------------------------------------------------------------------------
__global__ __launch_bounds__(512) void precompute(
    const float* __restrict__ t2v, const float* __restrict__ A,
    const float* __restrict__ B,
    ushort* __restrict__ tBp, ushort* __restrict__ Atp)
{
  __shared__ float row[256];
  const int b = blockIdx.x, tid = threadIdx.x;
  if (b < TOPICS) {
    const int t = b;
    if (tid < 256) row[tid] = t2v[(size_t)t * 256 + tid];
    __syncthreads();
    if (tid < 256) {
      const int d = tid;
      const float4* rv = (const float4*)row;
      const float4* bv = (const float4*)(B + (size_t)d * 256);
      float acc = 0.f;
#pragma unroll 8
      for (int k = 0; k < 64; ++k) {
        float4 r = rv[k], x = bv[k];
        acc += r.x * x.x + r.y * x.y + r.z * x.z + r.w * x.w;
      }
      const int tile = t >> 4, ks = d >> 5;
      const int lane = (t & 15) | (((d >> 3) & 3) << 4);
      const int e = d & 7;
      tBp[((size_t)tile * 8 + ks) * 512 + lane * 8 + e] = bf16_rne(acc);
    }
  } else {
    const int d = b - TOPICS;
    if (tid < 256) row[tid] = A[(size_t)d * 256 + tid];
    __syncthreads();
    const int t = tid;
    const float4* rv = (const float4*)row;
    const float4* tv = (const float4*)(t2v + (size_t)t * 256);
    float acc = 0.f;
#pragma unroll 8
    for (int k = 0; k < 64; ++k) {
      float4 r = rv[k], x = tv[k];
      acc += r.x * x.x + r.y * x.y + r.z * x.z + r.w * x.w;
    }
    const int dtile = d >> 4, ks = t >> 5;
    const int lane = (d & 15) | (((t >> 3) & 3) << 4);
    const int e = t & 7;
    Atp[((size_t)dtile * 16 + ks) * 512 + lane * 8 + e] = bf16_rne(acc);
  }
}

// ---------------------------------------------------------------------------
// s-kernel: R11 fused_main minus mu/P/PA. W pitch 280 (2-way banks).
// Produces: s, alpha, RL partials.
// ---------------------------------------------------------------------------
__global__ __launch_bounds__(256, 4) void s_main(
    const float* __restrict__ w2v,
    const ushort* __restrict__ tBp, const float* __restrict__ sigma,
    float* __restrict__ out_alpha, float* __restrict__ out_s,
    float* __restrict__ part_rs, float* __restrict__ part_ss, int do_rl)
{
  __shared__ ushort Whi[VT][280];   // pitch 280: 140 dwords, %32=12 -> ~2-way
  __shared__ ushort Wlo[VT][280];
  __shared__ float red[4][VT];
  __shared__ float rs_lds[TOPICS];

  const int tid  = threadIdx.x;
  const int wave = tid >> 6, lane = tid & 63;
  const int lr = lane & 15, lg = lane >> 4;
  const int vb = blockIdx.x * VT;

  // ---- prefetch first 4 ring slots (steps 0..3) ----
  const ushort* sbase = tBp + (size_t)wave * 32768 + lane * 8;
  short8 Ah[4];
#pragma unroll
  for (int i = 0; i < 4; ++i)
    Ah[i] = *(const short8*)(sbase + (size_t)i * 4096);

  // ---- stage W hi/lo ----
#pragma unroll
  for (int it = 0; it < 8; ++it) {
    int j = tid + (it << 8);
    int v = j >> 6, q = j & 63;
    int vr = min(vb + v, VOCAB - 1);
    float4 x = *(const float4*)(w2v + (size_t)vr * 256 + (q << 2));
    float xs[4] = {x.x, x.y, x.z, x.w};
    ushort h[4], l[4];
#pragma unroll
    for (int i = 0; i < 4; ++i) {
      ushort hi = bf16_rne(xs[i]);
      h[i] = hi;
      l[i] = bf16_rne(xs[i] - bf16f(hi));
    }
    *(uint2*)&Whi[v][q << 2] = make_uint2((uint)h[0] | ((uint)h[1] << 16),
                                          (uint)h[2] | ((uint)h[3] << 16));
    *(uint2*)&Wlo[v][q << 2] = make_uint2((uint)l[0] | ((uint)l[1] << 16),
                                          (uint)l[2] | ((uint)l[3] << 16));
  }
  __syncthreads();

  // ---- s-GEMM: ring depth 4 steps, 4 MFMA/step ----
  f32x4 acc[8][2];
#pragma unroll
  for (int mi = 0; mi < 8; ++mi)
#pragma unroll
    for (int nj = 0; nj < 2; ++nj) acc[mi][nj] = (f32x4){0.f, 0.f, 0.f, 0.f};

#pragma unroll
  for (int ks = 0; ks < 8; ++ks) {
    const int k0 = (ks << 5) + (lg << 3);
    short8 bh[2], bl[2];
#pragma unroll
    for (int nj = 0; nj < 2; ++nj) {
      bh[nj] = *(const short8*)&Whi[(nj << 4) + lr][k0];
      bl[nj] = *(const short8*)&Wlo[(nj << 4) + lr][k0];
    }
#pragma unroll
    for (int mi = 0; mi < 8; ++mi) {
      const int n = (ks << 3) + mi;
      short8 ah = Ah[n & 3];
      if (n + 4 < 64) {
        const int n4 = n + 4;
        Ah[n & 3] = *(const short8*)(sbase + (size_t)(n4 & 7) * 4096
                                           + (size_t)(n4 >> 3) * 512);
      }
#pragma unroll
      for (int nj = 0; nj < 2; ++nj) {
        acc[mi][nj] = __builtin_amdgcn_mfma_f32_16x16x32_bf16(ah, bh[nj], acc[mi][nj], 0, 0, 0);
        acc[mi][nj] = __builtin_amdgcn_mfma_f32_16x16x32_bf16(ah, bl[nj], acc[mi][nj], 0, 0, 0);
      }
    }
  }

  // ---- write s (interleaved, D layout: col=lr, row=lg*4+r) ----
#pragma unroll
  for (int mi = 0; mi < 8; ++mi) {
    const int t = (wave << 7) + (mi << 4) + (lg << 2);
#pragma unroll
    for (int r = 0; r < 4; ++r)
#pragma unroll
      for (int nj = 0; nj < 2; ++nj) {
        const int v = vb + (nj << 4) + lr;
        if (v < VOCAB) out_s[(size_t)(t + r) * VOCAB + v] = acc[mi][nj][r];
      }
  }

  // ---- softmax max ----
  float gmax[2];
  {
    float pm[2] = {-3.4e38f, -3.4e38f};
#pragma unroll
    for (int mi = 0; mi < 8; ++mi)
#pragma unroll
      for (int nj = 0; nj < 2; ++nj)
#pragma unroll
        for (int r = 0; r < 4; ++r) pm[nj] = fmaxf(pm[nj], acc[mi][nj][r]);
#pragma unroll
    for (int nj = 0; nj < 2; ++nj) {
      pm[nj] = fmaxf(pm[nj], __shfl_xor(pm[nj], 16));
      pm[nj] = fmaxf(pm[nj], __shfl_xor(pm[nj], 32));
    }
    if (lg == 0) { red[wave][lr] = pm[0]; red[wave][16 + lr] = pm[1]; }
  }
  __syncthreads();
#pragma unroll
  for (int nj = 0; nj < 2; ++nj) {
    const int c = (nj << 4) + lr;
    gmax[nj] = fmaxf(fmaxf(red[0][c], red[1][c]), fmaxf(red[2][c], red[3][c]));
  }
  __syncthreads();

  // ---- exp + sum -> inv ----
  float inv[2];
  {
    float ps[2] = {0.f, 0.f};
#pragma unroll
    for (int mi = 0; mi < 8; ++mi)
#pragma unroll
      for (int nj = 0; nj < 2; ++nj)
#pragma unroll
        for (int r = 0; r < 4; ++r) {
          float e = __expf(acc[mi][nj][r] - gmax[nj]);
          acc[mi][nj][r] = e;
          ps[nj] += e;
        }
#pragma unroll
    for (int nj = 0; nj < 2; ++nj) {
      ps[nj] += __shfl_xor(ps[nj], 16);
      ps[nj] += __shfl_xor(ps[nj], 32);
    }
    if (lg == 0) { red[wave][lr] = ps[0]; red[wave][16 + lr] = ps[1]; }
  }
  __syncthreads();
#pragma unroll
  for (int nj = 0; nj < 2; ++nj) {
    const int c = (nj << 4) + lr;
    inv[nj] = 1.0f / (red[0][c] + red[1][c] + red[2][c] + red[3][c]);
  }

  // ---- alpha = exp*inv: store fp32 + RL partials ----
  float ssq = 0.f;
#pragma unroll
  for (int mi = 0; mi < 8; ++mi) {
    const int tb = (wave << 7) + (mi << 4) + (lg << 2);
#pragma unroll
    for (int nj = 0; nj < 2; ++nj) {
#pragma unroll
      for (int r = 0; r < 4; ++r) acc[mi][nj][r] *= inv[nj];
      const int v = vb + (nj << 4) + lr;
      if (v < VOCAB) {
#pragma unroll
        for (int r = 0; r < 4; ++r)
          out_alpha[(size_t)(tb + r) * VOCAB + v] = acc[mi][nj][r];
      }
    }
    if (do_rl) {
#pragma unroll
      for (int r = 0; r < 4; ++r) {
        float rowp = 0.f;
#pragma unroll
        for (int nj = 0; nj < 2; ++nj) {
          float a = acc[mi][nj][r];
          float am = (vb + (nj << 4) + lr < VOCAB) ? a : 0.f;
          rowp += am;
          ssq = fmaf(am, am, ssq);
        }
        rowp += __shfl_xor(rowp, 1);
        rowp += __shfl_xor(rowp, 2);
        rowp += __shfl_xor(rowp, 4);
        rowp += __shfl_xor(rowp, 8);
        if (lr == 0) rs_lds[tb + r] = rowp;
      }
    }
  }
  __syncthreads();

  if (do_rl) {
    part_rs[(size_t)blockIdx.x * TOPICS + tid]       = rs_lds[tid];
    part_rs[(size_t)blockIdx.x * TOPICS + 256 + tid] = rs_lds[256 + tid];
    ssq += __shfl_xor(ssq, 1);
    ssq += __shfl_xor(ssq, 2);
    ssq += __shfl_xor(ssq, 4);
    ssq += __shfl_xor(ssq, 8);
    ssq += __shfl_xor(ssq, 16);
    ssq += __shfl_xor(ssq, 32);
    if (lane == 0) part_ss[blockIdx.x * 4 + wave] = ssq;
  }
}

// ---------------------------------------------------------------------------
// mu-kernel: 16 vocab cols per block, 3125 blocks, 4 waves. No bulk stores
// (L2 stays clean -> At panel L2-resident), small acc (16 regs) -> high occ.
// Stages alpha (fp32, L3-hot) -> bf16 LDS tile, then mu-GEMM + P.
// ---------------------------------------------------------------------------
__global__ __launch_bounds__(256, 4) void mu_main(
    const float* __restrict__ w2v, const ushort* __restrict__ Atp,
    const float* __restrict__ sigma, const float* __restrict__ alpha,
    float* __restrict__ out_P)
{
  __shared__ ushort PB[16][536];    // pitch 536: 268 dwords, %32=12 -> ~2-way
  __shared__ float red2[4][16];

  const int tid  = threadIdx.x;
  const int wave = tid >> 6, lane = tid & 63;
  const int lr = lane & 15, lg = lane >> 4;
  const int vb = blockIdx.x * 16;

  // ---- prefetch first 4 At ring slots ----
  const ushort* mbase = Atp + (size_t)wave * 32768 + lane * 8;
  short8 Mh[4];
#pragma unroll
  for (int i = 0; i < 4; ++i)
    Mh[i] = *(const short8*)(mbase + (size_t)i * 8192);

  // ---- stage alpha -> PB bf16 (v = tid&15 -> coalesced 64B row segments) ----
  {
    const int v = tid & 15, t0 = tid >> 4;
#pragma unroll 4
    for (int it = 0; it < 32; ++it) {
      const int t = t0 + (it << 4);
      PB[v][t] = bf16_rne(alpha[(size_t)t * VOCAB + vb + v]);
    }
  }
  __syncthreads();

  // ---- mu-GEMM: macc[mi], d-rows = wave*64 + mi*16, K=512, ring depth 4 ----
  f32x4 macc[4];
#pragma unroll
  for (int mi = 0; mi < 4; ++mi) macc[mi] = (f32x4){0.f, 0.f, 0.f, 0.f};

#pragma unroll
  for (int ks = 0; ks < 16; ++ks) {
    const int k0 = (ks << 5) + (lg << 3);
    short8 pb = *(const short8*)&PB[lr][k0];
#pragma unroll
    for (int mi = 0; mi < 4; ++mi) {
      const int n = (ks << 2) + mi;
      short8 ah = Mh[n & 3];
      if (n + 4 < 64) {
        const int n4 = n + 4;
        Mh[n & 3] = *(const short8*)(mbase + (size_t)(n4 & 3) * 8192
                                           + (size_t)(n4 >> 2) * 512);
      }
      macc[mi] = __builtin_amdgcn_mfma_f32_16x16x32_bf16(ah, pb, macc[mi], 0, 0, 0);
    }
  }

  // ---- P: sum_d (w2v - mu)^2 ----
  {
    float pp = 0.f;
    const int v = vb + lr;   // always < VOCAB (3125*16 == 50000)
#pragma unroll
    for (int mi = 0; mi < 4; ++mi) {
      const int dbase = (wave << 6) + (mi << 4) + (lg << 2);
      float4 w = *(const float4*)(w2v + (size_t)v * 256 + dbase);
      float d0 = w.x - macc[mi][0];
      float d1 = w.y - macc[mi][1];
      float d2 = w.z - macc[mi][2];
      float d3 = w.w - macc[mi][3];
      pp += d0 * d0 + d1 * d1 + d2 * d2 + d3 * d3;
    }
    pp += __shfl_xor(pp, 16);
    pp += __shfl_xor(pp, 32);
    if (lg == 0) red2[wave][lr] = pp;
  }
  __syncthreads();
  if (tid < 16) {
    float sum = red2[0][tid] + red2[1][tid] + red2[2][tid] + red2[3][tid];
    out_P[vb + tid] = sum / sigma[0];
  }
}

// ---------------------------------------------------------------------------
// RL pass 2: rowsum[t] = sum_blk part_rs[blk][t]. One block per topic.
// ---------------------------------------------------------------------------
__global__ __launch_bounds__(256) void rl_pass2(
    const float* __restrict__ part_rs, float* __restrict__ rowsum)
{
  const int t = blockIdx.x;
  float s = 0.f;
  for (int i = threadIdx.x; i < NBLK; i += 256)
    s += part_rs[(size_t)i * TOPICS + t];
  __shared__ float lsum[4];
  const int lane = threadIdx.x & 63, wave = threadIdx.x >> 6;
#pragma unroll
  for (int off = 32; off > 0; off >>= 1) s += __shfl_xor(s, off);
  if (lane == 0) lsum[wave] = s;
  __syncthreads();
  if (threadIdx.x == 0) rowsum[t] = lsum[0] + lsum[1] + lsum[2] + lsum[3];
}

__global__ __launch_bounds__(512) void rl_final_new(
    const float* __restrict__ rowsum, const float* __restrict__ part_ss,
    const float* __restrict__ sigma, float* __restrict__ out_RL,
    float* __restrict__ out_sigma)
{
  const int t = threadIdx.x;
  float b = rowsum[t] * rowsum[t];
  float a = 0.f;
  for (int i = t; i < NBLK * 4; i += 512) a += part_ss[i];
  __shared__ float la[8], lb[8];
  const int lane = t & 63, wave = t >> 6;
#pragma unroll
  for (int off = 32; off > 0; off >>= 1) {
    a += __shfl_xor(a, off);
    b += __shfl_xor(b, off);
  }
  if (lane == 0) { la[wave] = a; lb[wave] = b; }
  __syncthreads();
  if (t == 0) {
    float sa = 0.f, sb = 0.f;
#pragma unroll
    for (int w = 0; w < 8; ++w) { sa += la[w]; sb += lb[w]; }
    out_RL[0] = sa - sb / (float)VOCAB;
    out_sigma[0] = sigma[0];
  }
}

// ---------------------------------------------------------------------------
// Fallback (small ws): alpha re-read path
// ---------------------------------------------------------------------------
__global__ __launch_bounds__(256) void row_reduce(
    const float* __restrict__ alpha, float* __restrict__ rowsum, float* __restrict__ ssum)
{
  const int t = blockIdx.x;
  const float4* base = (const float4*)(alpha + (size_t)t * VOCAB);
  float rs = 0.f, ss = 0.f;
  for (int i = threadIdx.x; i < VOCAB / 4; i += 256) {
    float4 a = base[i];
    rs += a.x + a.y + a.z + a.w;
    ss += a.x * a.x + a.y * a.y + a.z * a.z + a.w * a.w;
  }
  __shared__ float lr[4], ls[4];
  const int lane = threadIdx.x & 63, wave = threadIdx.x >> 6;
#pragma unroll
  for (int off = 32; off > 0; off >>= 1) {
    rs += __shfl_xor(rs, off);
    ss += __shfl_xor(ss, off);
  }
  if (lane == 0) { lr[wave] = rs; ls[wave] = ss; }
  __syncthreads();
  if (threadIdx.x == 0) {
    rowsum[t] = lr[0] + lr[1] + lr[2] + lr[3];
    ssum[t]   = ls[0] + ls[1] + ls[2] + ls[3];
  }
}

__global__ __launch_bounds__(512) void rl_final_old(
    const float* __restrict__ rowsum, const float* __restrict__ ssum,
    const float* __restrict__ sigma, float* __restrict__ out_RL,
    float* __restrict__ out_sigma)
{
  const int t = threadIdx.x;
  float a = ssum[t];
  float b = rowsum[t] * rowsum[t];
  __shared__ float la[8], lb[8];
  const int lane = t & 63, wave = t >> 6;
#pragma unroll
  for (int off = 32; off > 0; off >>= 1) {
    a += __shfl_xor(a, off);
    b += __shfl_xor(b, off);
  }
  if (lane == 0) { la[wave] = a; lb[wave] = b; }
  __syncthreads();
  if (t == 0) {
    float sa = 0.f, sb = 0.f;
#pragma unroll
    for (int w = 0; w < 8; ++w) { sa += la[w]; sb += lb[w]; }
    out_RL[0] = sa - sb / (float)VOCAB;
    out_sigma[0] = sigma[0];
  }
}

extern "C" void kernel_launch(void* const* d_in, const int* in_sizes, int n_in,
                              void* d_out, int out_size, void* d_ws, size_t ws_size,
                              hipStream_t stream) {
  const float* w2v   = (const float*)d_in[0];  // [50000][256]
  const float* t2v   = (const float*)d_in[1];  // [512][256]
  const float* A     = (const float*)d_in[2];  // [256][256]
  const float* B     = (const float*)d_in[3];  // [256][256]
  const float* sigma = (const float*)d_in[4];  // [1]

  float* out       = (float*)d_out;
  float* out_alpha = out;                                  // 25,600,000
  float* out_P     = out + (size_t)TOPICS * VOCAB;         // 50,000
  float* out_RL    = out_P + VOCAB;                        // 1
  float* out_s     = out_RL + 1;                           // 25,600,000
  float* out_sigma = out_s + (size_t)TOPICS * VOCAB;       // 1

  ushort* tBp = (ushort*)d_ws;                             // 131072 ushorts (256 KB)
  ushort* Atp = tBp + (size_t)131072;                      // 131072 ushorts (256 KB)
  float* tail = (float*)(Atp + (size_t)131072);
  float* part_rs = tail;                                   // [NBLK][512]
  float* part_ss = part_rs + (size_t)NBLK * TOPICS;        // 1563*4
  float* rowsum  = part_ss + (size_t)NBLK * 4;             // 512
  size_t need = (size_t)(2 * 131072) * 2 +
                ((size_t)NBLK * TOPICS + (size_t)NBLK * 4 + TOPICS) * 4;
  const int do_rl = (ws_size >= need) ? 1 : 0;

  precompute<<<TOPICS + VDIM, 512, 0, stream>>>(t2v, A, B, tBp, Atp);

  s_main<<<NBLK, 256, 0, stream>>>(w2v, tBp, sigma, out_alpha, out_s,
                                   part_rs, part_ss, do_rl);

  mu_main<<<NBLK16, 256, 0, stream>>>(w2v, Atp, sigma, out_alpha, out_P);

  if (do_rl) {
    rl_pass2<<<TOPICS, 256, 0, stream>>>(part_rs, rowsum);
    rl_final_new<<<1, 512, 0, stream>>>(rowsum, part_ss, sigma, out_RL, out_sigma);
  } else {
    float* rs_old = tail;
    float* ss_old = rs_old + TOPICS;
    row_reduce<<<TOPICS, 256, 0, stream>>>(out_alpha, rs_old, ss_old);
    rl_final_old<<<1, 512, 0, stream>>>(rs_old, ss_old, sigma, out_RL, out_sigma);
  }
}

// Round 13
// 186.396 us; speedup vs baseline: 1.0511x; 1.0511x over previous
//
#include <hip/hip_runtime.h>

#define VOCAB 50000
#define VDIM 256
#define TOPICS 512
#define VT 32
#define NBLK 1563    // ceil(VOCAB/32)  (s kernel)
#define NBLK16 3125  // VOCAB/16        (mu kernel, exact)
#define NXCD 8

typedef unsigned int uint;
typedef unsigned short ushort;
using short8 = __attribute__((ext_vector_type(8))) short;
using f32x4  = __attribute__((ext_vector_type(4))) float;

__device__ __forceinline__ ushort bf16_rne(float f) {
  uint u = __float_as_uint(f);
  u += 0x7FFFu + ((u >> 16) & 1u);
  return (ushort)(u >> 16);
}
__device__ __forceinline__ float bf16f(ushort h) {
  return __uint_as_float(((uint)h) << 16);
}

// Bijective chunked XCD swizzle (m204): consecutive logical ids -> same XCD.
__device__ __forceinline__ int xcd_swizzle(int orig, int nwg) {
  const int q = nwg / NXCD, r = nwg % NXCD;
  const int xcd = orig % NXCD, i = orig / NXCD;
  return (xcd < r ? xcd * (q + 1) : r * (q + 1) + (xcd - r) * q) + i;
}

// ---------------------------------------------------------------------------
// Precompute, single-plane bf16 fragment-major packing:
//   tBp[tile=t>>4][ks=d>>5][lane=(t&15)|(((d>>3)&3)<<4)][e=d&7]   (256 KB)
//   Atp[dtile=d>>4][ks=t>>5][lane=(d&15)|(((t>>3)&3)<<4)][e=t&7]  (256 KB)
// ---------------------------------------------------------------------------
__global__ __launch_bounds__(512) void precompute(
    const float* __restrict__ t2v, const float* __restrict__ A,
    const float* __restrict__ B,
    ushort* __restrict__ tBp, ushort* __restrict__ Atp)
{
  __shared__ float row[256];
  const int b = blockIdx.x, tid = threadIdx.x;
  if (b < TOPICS) {
    const int t = b;
    if (tid < 256) row[tid] = t2v[(size_t)t * 256 + tid];
    __syncthreads();
    if (tid < 256) {
      const int d = tid;
      const float4* rv = (const float4*)row;
      const float4* bv = (const float4*)(B + (size_t)d * 256);
      float acc = 0.f;
#pragma unroll 8
      for (int k = 0; k < 64; ++k) {
        float4 r = rv[k], x = bv[k];
        acc += r.x * x.x + r.y * x.y + r.z * x.z + r.w * x.w;
      }
      const int tile = t >> 4, ks = d >> 5;
      const int lane = (t & 15) | (((d >> 3) & 3) << 4);
      const int e = d & 7;
      tBp[((size_t)tile * 8 + ks) * 512 + lane * 8 + e] = bf16_rne(acc);
    }
  } else {
    const int d = b - TOPICS;
    if (tid < 256) row[tid] = A[(size_t)d * 256 + tid];
    __syncthreads();
    const int t = tid;
    const float4* rv = (const float4*)row;
    const float4* tv = (const float4*)(t2v + (size_t)t * 256);
    float acc = 0.f;
#pragma unroll 8
    for (int k = 0; k < 64; ++k) {
      float4 r = rv[k], x = tv[k];
      acc += r.x * x.x + r.y * x.y + r.z * x.z + r.w * x.w;
    }
    const int dtile = d >> 4, ks = t >> 5;
    const int lane = (d & 15) | (((t >> 3) & 3) << 4);
    const int e = t & 7;
    Atp[((size_t)dtile * 16 + ks) * 512 + lane * 8 + e] = bf16_rne(acc);
  }
}

// ---------------------------------------------------------------------------
// s-kernel (R12 + XCD swizzle): produces s, alpha, RL partials.
// ---------------------------------------------------------------------------
__global__ __launch_bounds__(256, 4) void s_main(
    const float* __restrict__ w2v,
    const ushort* __restrict__ tBp, const float* __restrict__ sigma,
    float* __restrict__ out_alpha, float* __restrict__ out_s,
    float* __restrict__ part_rs, float* __restrict__ part_ss, int do_rl)
{
  __shared__ ushort Whi[VT][280];   // pitch 280: ~2-way banks
  __shared__ ushort Wlo[VT][280];
  __shared__ float red[4][VT];
  __shared__ float rs_lds[TOPICS];

  const int tid  = threadIdx.x;
  const int wave = tid >> 6, lane = tid & 63;
  const int lr = lane & 15, lg = lane >> 4;
  const int bid = xcd_swizzle(blockIdx.x, NBLK);   // logical block id
  const int vb = bid * VT;

  // ---- prefetch first 4 ring slots (steps 0..3) ----
  const ushort* sbase = tBp + (size_t)wave * 32768 + lane * 8;
  short8 Ah[4];
#pragma unroll
  for (int i = 0; i < 4; ++i)
    Ah[i] = *(const short8*)(sbase + (size_t)i * 4096);

  // ---- stage W hi/lo ----
#pragma unroll
  for (int it = 0; it < 8; ++it) {
    int j = tid + (it << 8);
    int v = j >> 6, q = j & 63;
    int vr = min(vb + v, VOCAB - 1);
    float4 x = *(const float4*)(w2v + (size_t)vr * 256 + (q << 2));
    float xs[4] = {x.x, x.y, x.z, x.w};
    ushort h[4], l[4];
#pragma unroll
    for (int i = 0; i < 4; ++i) {
      ushort hi = bf16_rne(xs[i]);
      h[i] = hi;
      l[i] = bf16_rne(xs[i] - bf16f(hi));
    }
    *(uint2*)&Whi[v][q << 2] = make_uint2((uint)h[0] | ((uint)h[1] << 16),
                                          (uint)h[2] | ((uint)h[3] << 16));
    *(uint2*)&Wlo[v][q << 2] = make_uint2((uint)l[0] | ((uint)l[1] << 16),
                                          (uint)l[2] | ((uint)l[3] << 16));
  }
  __syncthreads();

  // ---- s-GEMM: ring depth 4 steps, 4 MFMA/step ----
  f32x4 acc[8][2];
#pragma unroll
  for (int mi = 0; mi < 8; ++mi)
#pragma unroll
    for (int nj = 0; nj < 2; ++nj) acc[mi][nj] = (f32x4){0.f, 0.f, 0.f, 0.f};

#pragma unroll
  for (int ks = 0; ks < 8; ++ks) {
    const int k0 = (ks << 5) + (lg << 3);
    short8 bh[2], bl[2];
#pragma unroll
    for (int nj = 0; nj < 2; ++nj) {
      bh[nj] = *(const short8*)&Whi[(nj << 4) + lr][k0];
      bl[nj] = *(const short8*)&Wlo[(nj << 4) + lr][k0];
    }
#pragma unroll
    for (int mi = 0; mi < 8; ++mi) {
      const int n = (ks << 3) + mi;
      short8 ah = Ah[n & 3];
      if (n + 4 < 64) {
        const int n4 = n + 4;
        Ah[n & 3] = *(const short8*)(sbase + (size_t)(n4 & 7) * 4096
                                           + (size_t)(n4 >> 3) * 512);
      }
#pragma unroll
      for (int nj = 0; nj < 2; ++nj) {
        acc[mi][nj] = __builtin_amdgcn_mfma_f32_16x16x32_bf16(ah, bh[nj], acc[mi][nj], 0, 0, 0);
        acc[mi][nj] = __builtin_amdgcn_mfma_f32_16x16x32_bf16(ah, bl[nj], acc[mi][nj], 0, 0, 0);
      }
    }
  }

  // ---- write s (interleaved, D layout: col=lr, row=lg*4+r) ----
#pragma unroll
  for (int mi = 0; mi < 8; ++mi) {
    const int t = (wave << 7) + (mi << 4) + (lg << 2);
#pragma unroll
    for (int r = 0; r < 4; ++r)
#pragma unroll
      for (int nj = 0; nj < 2; ++nj) {
        const int v = vb + (nj << 4) + lr;
        if (v < VOCAB) out_s[(size_t)(t + r) * VOCAB + v] = acc[mi][nj][r];
      }
  }

  // ---- softmax max ----
  float gmax[2];
  {
    float pm[2] = {-3.4e38f, -3.4e38f};
#pragma unroll
    for (int mi = 0; mi < 8; ++mi)
#pragma unroll
      for (int nj = 0; nj < 2; ++nj)
#pragma unroll
        for (int r = 0; r < 4; ++r) pm[nj] = fmaxf(pm[nj], acc[mi][nj][r]);
#pragma unroll
    for (int nj = 0; nj < 2; ++nj) {
      pm[nj] = fmaxf(pm[nj], __shfl_xor(pm[nj], 16));
      pm[nj] = fmaxf(pm[nj], __shfl_xor(pm[nj], 32));
    }
    if (lg == 0) { red[wave][lr] = pm[0]; red[wave][16 + lr] = pm[1]; }
  }
  __syncthreads();
#pragma unroll
  for (int nj = 0; nj < 2; ++nj) {
    const int c = (nj << 4) + lr;
    gmax[nj] = fmaxf(fmaxf(red[0][c], red[1][c]), fmaxf(red[2][c], red[3][c]));
  }
  __syncthreads();

  // ---- exp + sum -> inv ----
  float inv[2];
  {
    float ps[2] = {0.f, 0.f};
#pragma unroll
    for (int mi = 0; mi < 8; ++mi)
#pragma unroll
      for (int nj = 0; nj < 2; ++nj)
#pragma unroll
        for (int r = 0; r < 4; ++r) {
          float e = __expf(acc[mi][nj][r] - gmax[nj]);
          acc[mi][nj][r] = e;
          ps[nj] += e;
        }
#pragma unroll
    for (int nj = 0; nj < 2; ++nj) {
      ps[nj] += __shfl_xor(ps[nj], 16);
      ps[nj] += __shfl_xor(ps[nj], 32);
    }
    if (lg == 0) { red[wave][lr] = ps[0]; red[wave][16 + lr] = ps[1]; }
  }
  __syncthreads();
#pragma unroll
  for (int nj = 0; nj < 2; ++nj) {
    const int c = (nj << 4) + lr;
    inv[nj] = 1.0f / (red[0][c] + red[1][c] + red[2][c] + red[3][c]);
  }

  // ---- alpha = exp*inv: store fp32 + RL partials ----
  float ssq = 0.f;
#pragma unroll
  for (int mi = 0; mi < 8; ++mi) {
    const int tb = (wave << 7) + (mi << 4) + (lg << 2);
#pragma unroll
    for (int nj = 0; nj < 2; ++nj) {
#pragma unroll
      for (int r = 0; r < 4; ++r) acc[mi][nj][r] *= inv[nj];
      const int v = vb + (nj << 4) + lr;
      if (v < VOCAB) {
#pragma unroll
        for (int r = 0; r < 4; ++r)
          out_alpha[(size_t)(tb + r) * VOCAB + v] = acc[mi][nj][r];
      }
    }
    if (do_rl) {
#pragma unroll
      for (int r = 0; r < 4; ++r) {
        float rowp = 0.f;
#pragma unroll
        for (int nj = 0; nj < 2; ++nj) {
          float a = acc[mi][nj][r];
          float am = (vb + (nj << 4) + lr < VOCAB) ? a : 0.f;
          rowp += am;
          ssq = fmaf(am, am, ssq);
        }
        rowp += __shfl_xor(rowp, 1);
        rowp += __shfl_xor(rowp, 2);
        rowp += __shfl_xor(rowp, 4);
        rowp += __shfl_xor(rowp, 8);
        if (lr == 0) rs_lds[tb + r] = rowp;
      }
    }
  }
  __syncthreads();

  if (do_rl) {
    part_rs[(size_t)bid * TOPICS + tid]       = rs_lds[tid];
    part_rs[(size_t)bid * TOPICS + 256 + tid] = rs_lds[256 + tid];
    ssq += __shfl_xor(ssq, 1);
    ssq += __shfl_xor(ssq, 2);
    ssq += __shfl_xor(ssq, 4);
    ssq += __shfl_xor(ssq, 8);
    ssq += __shfl_xor(ssq, 16);
    ssq += __shfl_xor(ssq, 32);
    if (lane == 0) part_ss[bid * 4 + wave] = ssq;
  }
}

// ---------------------------------------------------------------------------
// mu-kernel: 16 cols/block, 3125 blocks. (256,6) -> 6 blocks/CU (24 waves).
// ---------------------------------------------------------------------------
__global__ __launch_bounds__(256, 6) void mu_main(
    const float* __restrict__ w2v, const ushort* __restrict__ Atp,
    const float* __restrict__ sigma, const float* __restrict__ alpha,
    float* __restrict__ out_P)
{
  __shared__ ushort PB[16][536];    // pitch 536: ~2-way banks
  __shared__ float red2[4][16];

  const int tid  = threadIdx.x;
  const int wave = tid >> 6, lane = tid & 63;
  const int lr = lane & 15, lg = lane >> 4;
  const int vb = blockIdx.x * 16;

  // ---- prefetch first 4 At ring slots ----
  const ushort* mbase = Atp + (size_t)wave * 32768 + lane * 8;
  short8 Mh[4];
#pragma unroll
  for (int i = 0; i < 4; ++i)
    Mh[i] = *(const short8*)(mbase + (size_t)i * 8192);

  // ---- stage alpha -> PB bf16 ----
  {
    const int v = tid & 15, t0 = tid >> 4;
#pragma unroll 4
    for (int it = 0; it < 32; ++it) {
      const int t = t0 + (it << 4);
      PB[v][t] = bf16_rne(alpha[(size_t)t * VOCAB + vb + v]);
    }
  }
  __syncthreads();

  // ---- mu-GEMM: macc[mi], d-rows = wave*64 + mi*16, K=512, ring depth 4 ----
  f32x4 macc[4];
#pragma unroll
  for (int mi = 0; mi < 4; ++mi) macc[mi] = (f32x4){0.f, 0.f, 0.f, 0.f};

#pragma unroll
  for (int ks = 0; ks < 16; ++ks) {
    const int k0 = (ks << 5) + (lg << 3);
    short8 pb = *(const short8*)&PB[lr][k0];
#pragma unroll
    for (int mi = 0; mi < 4; ++mi) {
      const int n = (ks << 2) + mi;
      short8 ah = Mh[n & 3];
      if (n + 4 < 64) {
        const int n4 = n + 4;
        Mh[n & 3] = *(const short8*)(mbase + (size_t)(n4 & 3) * 8192
                                           + (size_t)(n4 >> 2) * 512);
      }
      macc[mi] = __builtin_amdgcn_mfma_f32_16x16x32_bf16(ah, pb, macc[mi], 0, 0, 0);
    }
  }

  // ---- P: sum_d (w2v - mu)^2 ----
  {
    float pp = 0.f;
    const int v = vb + lr;   // always < VOCAB (3125*16 == 50000)
#pragma unroll
    for (int mi = 0; mi < 4; ++mi) {
      const int dbase = (wave << 6) + (mi << 4) + (lg << 2);
      float4 w = *(const float4*)(w2v + (size_t)v * 256 + dbase);
      float d0 = w.x - macc[mi][0];
      float d1 = w.y - macc[mi][1];
      float d2 = w.z - macc[mi][2];
      float d3 = w.w - macc[mi][3];
      pp += d0 * d0 + d1 * d1 + d2 * d2 + d3 * d3;
    }
    pp += __shfl_xor(pp, 16);
    pp += __shfl_xor(pp, 32);
    if (lg == 0) red2[wave][lr] = pp;
  }
  __syncthreads();
  if (tid < 16) {
    float sum = red2[0][tid] + red2[1][tid] + red2[2][tid] + red2[3][tid];
    out_P[vb + tid] = sum / sigma[0];
  }
}

// ---------------------------------------------------------------------------
// RL pass 2: rowsum[t] = sum_blk part_rs[blk][t]. One block per topic.
// ---------------------------------------------------------------------------
__global__ __launch_bounds__(256) void rl_pass2(
    const float* __restrict__ part_rs, float* __restrict__ rowsum)
{
  const int t = blockIdx.x;
  float s = 0.f;
  for (int i = threadIdx.x; i < NBLK; i += 256)
    s += part_rs[(size_t)i * TOPICS + t];
  __shared__ float lsum[4];
  const int lane = threadIdx.x & 63, wave = threadIdx.x >> 6;
#pragma unroll
  for (int off = 32; off > 0; off >>= 1) s += __shfl_xor(s, off);
  if (lane == 0) lsum[wave] = s;
  __syncthreads();
  if (threadIdx.x == 0) rowsum[t] = lsum[0] + lsum[1] + lsum[2] + lsum[3];
}

__global__ __launch_bounds__(512) void rl_final_new(
    const float* __restrict__ rowsum, const float* __restrict__ part_ss,
    const float* __restrict__ sigma, float* __restrict__ out_RL,
    float* __restrict__ out_sigma)
{
  const int t = threadIdx.x;
  float b = rowsum[t] * rowsum[t];
  float a = 0.f;
  for (int i = t; i < NBLK * 4; i += 512) a += part_ss[i];
  __shared__ float la[8], lb[8];
  const int lane = t & 63, wave = t >> 6;
#pragma unroll
  for (int off = 32; off > 0; off >>= 1) {
    a += __shfl_xor(a, off);
    b += __shfl_xor(b, off);
  }
  if (lane == 0) { la[wave] = a; lb[wave] = b; }
  __syncthreads();
  if (t == 0) {
    float sa = 0.f, sb = 0.f;
#pragma unroll
    for (int w = 0; w < 8; ++w) { sa += la[w]; sb += lb[w]; }
    out_RL[0] = sa - sb / (float)VOCAB;
    out_sigma[0] = sigma[0];
  }
}

// ---------------------------------------------------------------------------
// Fallback (small ws): alpha re-read path
// ---------------------------------------------------------------------------
__global__ __launch_bounds__(256) void row_reduce(
    const float* __restrict__ alpha, float* __restrict__ rowsum, float* __restrict__ ssum)
{
  const int t = blockIdx.x;
  const float4* base = (const float4*)(alpha + (size_t)t * VOCAB);
  float rs = 0.f, ss = 0.f;
  for (int i = threadIdx.x; i < VOCAB / 4; i += 256) {
    float4 a = base[i];
    rs += a.x + a.y + a.z + a.w;
    ss += a.x * a.x + a.y * a.y + a.z * a.z + a.w * a.w;
  }
  __shared__ float lr[4], ls[4];
  const int lane = threadIdx.x & 63, wave = threadIdx.x >> 6;
#pragma unroll
  for (int off = 32; off > 0; off >>= 1) {
    rs += __shfl_xor(rs, off);
    ss += __shfl_xor(ss, off);
  }
  if (lane == 0) { lr[wave] = rs; ls[wave] = ss; }
  __syncthreads();
  if (threadIdx.x == 0) {
    rowsum[t] = lr[0] + lr[1] + lr[2] + lr[3];
    ssum[t]   = ls[0] + ls[1] + ls[2] + ls[3];
  }
}

__global__ __launch_bounds__(512) void rl_final_old(
    const float* __restrict__ rowsum, const float* __restrict__ ssum,
    const float* __restrict__ sigma, float* __restrict__ out_RL,
    float* __restrict__ out_sigma)
{
  const int t = threadIdx.x;
  float a = ssum[t];
  float b = rowsum[t] * rowsum[t];
  __shared__ float la[8], lb[8];
  const int lane = t & 63, wave = t >> 6;
#pragma unroll
  for (int off = 32; off > 0; off >>= 1) {
    a += __shfl_xor(a, off);
    b += __shfl_xor(b, off);
  }
  if (lane == 0) { la[wave] = a; lb[wave] = b; }
  __syncthreads();
  if (t == 0) {
    float sa = 0.f, sb = 0.f;
#pragma unroll
    for (int w = 0; w < 8; ++w) { sa += la[w]; sb += lb[w]; }
    out_RL[0] = sa - sb / (float)VOCAB;
    out_sigma[0] = sigma[0];
  }
}

extern "C" void kernel_launch(void* const* d_in, const int* in_sizes, int n_in,
                              void* d_out, int out_size, void* d_ws, size_t ws_size,
                              hipStream_t stream) {
  const float* w2v   = (const float*)d_in[0];  // [50000][256]
  const float* t2v   = (const float*)d_in[1];  // [512][256]
  const float* A     = (const float*)d_in[2];  // [256][256]
  const float* B     = (const float*)d_in[3];  // [256][256]
  const float* sigma = (const float*)d_in[4];  // [1]

  float* out       = (float*)d_out;
  float* out_alpha = out;                                  // 25,600,000
  float* out_P     = out + (size_t)TOPICS * VOCAB;         // 50,000
  float* out_RL    = out_P + VOCAB;                        // 1
  float* out_s     = out_RL + 1;                           // 25,600,000
  float* out_sigma = out_s + (size_t)TOPICS * VOCAB;       // 1

  ushort* tBp = (ushort*)d_ws;                             // 131072 ushorts (256 KB)
  ushort* Atp = tBp + (size_t)131072;                      // 131072 ushorts (256 KB)
  float* tail = (float*)(Atp + (size_t)131072);
  float* part_rs = tail;                                   // [NBLK][512]
  float* part_ss = part_rs + (size_t)NBLK * TOPICS;        // 1563*4
  float* rowsum  = part_ss + (size_t)NBLK * 4;             // 512
  size_t need = (size_t)(2 * 131072) * 2 +
                ((size_t)NBLK * TOPICS + (size_t)NBLK * 4 + TOPICS) * 4;
  const int do_rl = (ws_size >= need) ? 1 : 0;

  precompute<<<TOPICS + VDIM, 512, 0, stream>>>(t2v, A, B, tBp, Atp);

  s_main<<<NBLK, 256, 0, stream>>>(w2v, tBp, sigma, out_alpha, out_s,
                                   part_rs, part_ss, do_rl);

  mu_main<<<NBLK16, 256, 0, stream>>>(w2v, Atp, sigma, out_alpha, out_P);

  if (do_rl) {
    rl_pass2<<<TOPICS, 256, 0, stream>>>(part_rs, rowsum);
    rl_final_new<<<1, 512, 0, stream>>>(rowsum, part_ss, sigma, out_RL, out_sigma);
  } else {
    float* rs_old = tail;
    float* ss_old = rs_old + TOPICS;
    row_reduce<<<TOPICS, 256, 0, stream>>>(out_alpha, rs_old, ss_old);
    rl_final_old<<<1, 512, 0, stream>>>(rs_old, ss_old, sigma, out_RL, out_sigma);
  }
}

// Round 14
// 169.624 us; speedup vs baseline: 1.1550x; 1.0989x over previous
//
#include <hip/hip_runtime.h>

#define VOCAB 50000
#define VDIM 256
#define TOPICS 512
#define VT 32
#define NBLK 1563   // ceil(VOCAB/VT)
#define NXCD 8

typedef unsigned int uint;
typedef unsigned short ushort;
using short8 = __attribute__((ext_vector_type(8))) short;
using f32x4  = __attribute__((ext_vector_type(4))) float;

__device__ __forceinline__ ushort bf16_rne(float f) {
  uint u = __float_as_uint(f);
  u += 0x7FFFu + ((u >> 16) & 1u);
  return (ushort)(u >> 16);
}
__device__ __forceinline__ float bf16f(ushort h) {
  return __uint_as_float(((uint)h) << 16);
}
__device__ __forceinline__ uint packbf2(float a, float b) {
  return (uint)bf16_rne(a) | ((uint)bf16_rne(b) << 16);
}

// Bijective chunked XCD swizzle (m204): consecutive logical ids -> same XCD.
__device__ __forceinline__ int xcd_swizzle(int orig, int nwg) {
  const int q = nwg / NXCD, r = nwg % NXCD;
  const int xcd = orig % NXCD, i = orig / NXCD;
  return (xcd < r ? xcd * (q + 1) : r * (q + 1) + (xcd - r) * q) + i;
}

// ---------------------------------------------------------------------------
// Precompute, single-plane bf16 fragment-major packing:
//   tBp[tile=t>>4][ks=d>>5][lane=(t&15)|(((d>>3)&3)<<4)][e=d&7]   (256 KB)
//   Atp[dtile=d>>4][ks=t>>5][lane=(d&15)|(((t>>3)&3)<<4)][e=t&7]  (256 KB)
// ---------------------------------------------------------------------------
__global__ __launch_bounds__(512) void precompute(
    const float* __restrict__ t2v, const float* __restrict__ A,
    const float* __restrict__ B,
    ushort* __restrict__ tBp, ushort* __restrict__ Atp)
{
  __shared__ float row[256];
  const int b = blockIdx.x, tid = threadIdx.x;
  if (b < TOPICS) {
    const int t = b;
    if (tid < 256) row[tid] = t2v[(size_t)t * 256 + tid];
    __syncthreads();
    if (tid < 256) {
      const int d = tid;
      const float4* rv = (const float4*)row;
      const float4* bv = (const float4*)(B + (size_t)d * 256);
      float acc = 0.f;
#pragma unroll 8
      for (int k = 0; k < 64; ++k) {
        float4 r = rv[k], x = bv[k];
        acc += r.x * x.x + r.y * x.y + r.z * x.z + r.w * x.w;
      }
      const int tile = t >> 4, ks = d >> 5;
      const int lane = (t & 15) | (((d >> 3) & 3) << 4);
      const int e = d & 7;
      tBp[((size_t)tile * 8 + ks) * 512 + lane * 8 + e] = bf16_rne(acc);
    }
  } else {
    const int d = b - TOPICS;
    if (tid < 256) row[tid] = A[(size_t)d * 256 + tid];
    __syncthreads();
    const int t = tid;
    const float4* rv = (const float4*)row;
    const float4* tv = (const float4*)(t2v + (size_t)t * 256);
    float acc = 0.f;
#pragma unroll 8
    for (int k = 0; k < 64; ++k) {
      float4 r = rv[k], x = tv[k];
      acc += r.x * x.x + r.y * x.y + r.z * x.z + r.w * x.w;
    }
    const int dtile = d >> 4, ks = t >> 5;
    const int lane = (d & 15) | (((t >> 3) & 3) << 4);
    const int e = t & 7;
    Atp[((size_t)dtile * 16 + ks) * 512 + lane * 8 + e] = bf16_rne(acc);
  }
}

// ---------------------------------------------------------------------------
// Fused main — R11 structure (verified 195 µs) + XCD swizzle (verified +10 on
// split). Single-plane A panels, ring depth 4, interleaved stores, PA aliases
// W, RL partials via rs_lds + contiguous part_rs.
// ---------------------------------------------------------------------------
__global__ __launch_bounds__(256, 4) void fused_main(
    const float* __restrict__ w2v,
    const ushort* __restrict__ tBp, const ushort* __restrict__ Atp,
    const float* __restrict__ sigma,
    float* __restrict__ out_alpha, float* __restrict__ out_P,
    float* __restrict__ out_s,
    float* __restrict__ part_rs, float* __restrict__ part_ss, int do_rl)
{
  __shared__ __align__(16) char smem[33792];
  ushort (*Whi)[264] = (ushort (*)[264])smem;            // 16896 B
  ushort (*Wlo)[264] = (ushort (*)[264])(smem + 16896);  // 16896 B
  ushort (*PA)[520]  = (ushort (*)[520])smem;            // 33280 B (alias, W dead)
  __shared__ float red[4][VT];
  __shared__ float rs_lds[TOPICS];

  const int tid  = threadIdx.x;
  const int wave = tid >> 6, lane = tid & 63;
  const int lr = lane & 15, lg = lane >> 4;
  const int bid = xcd_swizzle(blockIdx.x, NBLK);
  const int vb = bid * VT;

  // ---- prefetch first 4 ring slots (steps 0..3) ----
  const ushort* sbase = tBp + (size_t)wave * 32768 + lane * 8;
  short8 Ah[4];
#pragma unroll
  for (int i = 0; i < 4; ++i)
    Ah[i] = *(const short8*)(sbase + (size_t)i * 4096);

  // ---- stage W hi/lo ----
#pragma unroll
  for (int it = 0; it < 8; ++it) {
    int j = tid + (it << 8);
    int v = j >> 6, q = j & 63;
    int vr = min(vb + v, VOCAB - 1);
    float4 x = *(const float4*)(w2v + (size_t)vr * 256 + (q << 2));
    float xs[4] = {x.x, x.y, x.z, x.w};
    ushort h[4], l[4];
#pragma unroll
    for (int i = 0; i < 4; ++i) {
      ushort hi = bf16_rne(xs[i]);
      h[i] = hi;
      l[i] = bf16_rne(xs[i] - bf16f(hi));
    }
    *(uint2*)&Whi[v][q << 2] = make_uint2((uint)h[0] | ((uint)h[1] << 16),
                                          (uint)h[2] | ((uint)h[3] << 16));
    *(uint2*)&Wlo[v][q << 2] = make_uint2((uint)l[0] | ((uint)l[1] << 16),
                                          (uint)l[2] | ((uint)l[3] << 16));
  }
  __syncthreads();

  // ---- s-GEMM: ring depth 4 steps, 4 MFMA/step ----
  f32x4 acc[8][2];
#pragma unroll
  for (int mi = 0; mi < 8; ++mi)
#pragma unroll
    for (int nj = 0; nj < 2; ++nj) acc[mi][nj] = (f32x4){0.f, 0.f, 0.f, 0.f};

#pragma unroll
  for (int ks = 0; ks < 8; ++ks) {
    const int k0 = (ks << 5) + (lg << 3);
    short8 bh[2], bl[2];
#pragma unroll
    for (int nj = 0; nj < 2; ++nj) {
      bh[nj] = *(const short8*)&Whi[(nj << 4) + lr][k0];
      bl[nj] = *(const short8*)&Wlo[(nj << 4) + lr][k0];
    }
#pragma unroll
    for (int mi = 0; mi < 8; ++mi) {
      const int n = (ks << 3) + mi;
      short8 ah = Ah[n & 3];
      if (n + 4 < 64) {
        const int n4 = n + 4;
        Ah[n & 3] = *(const short8*)(sbase + (size_t)(n4 & 7) * 4096
                                           + (size_t)(n4 >> 3) * 512);
      }
#pragma unroll
      for (int nj = 0; nj < 2; ++nj) {
        acc[mi][nj] = __builtin_amdgcn_mfma_f32_16x16x32_bf16(ah, bh[nj], acc[mi][nj], 0, 0, 0);
        acc[mi][nj] = __builtin_amdgcn_mfma_f32_16x16x32_bf16(ah, bl[nj], acc[mi][nj], 0, 0, 0);
      }
    }
  }

  // ---- write s (interleaved, D layout: col=lr, row=lg*4+r) ----
#pragma unroll
  for (int mi = 0; mi < 8; ++mi) {
    const int t = (wave << 7) + (mi << 4) + (lg << 2);
#pragma unroll
    for (int r = 0; r < 4; ++r)
#pragma unroll
      for (int nj = 0; nj < 2; ++nj) {
        const int v = vb + (nj << 4) + lr;
        if (v < VOCAB) out_s[(size_t)(t + r) * VOCAB + v] = acc[mi][nj][r];
      }
  }

  // ---- softmax max ----
  float gmax[2];
  {
    float pm[2] = {-3.4e38f, -3.4e38f};
#pragma unroll
    for (int mi = 0; mi < 8; ++mi)
#pragma unroll
      for (int nj = 0; nj < 2; ++nj)
#pragma unroll
        for (int r = 0; r < 4; ++r) pm[nj] = fmaxf(pm[nj], acc[mi][nj][r]);
#pragma unroll
    for (int nj = 0; nj < 2; ++nj) {
      pm[nj] = fmaxf(pm[nj], __shfl_xor(pm[nj], 16));
      pm[nj] = fmaxf(pm[nj], __shfl_xor(pm[nj], 32));
    }
    if (lg == 0) { red[wave][lr] = pm[0]; red[wave][16 + lr] = pm[1]; }
  }
  __syncthreads();
#pragma unroll
  for (int nj = 0; nj < 2; ++nj) {
    const int c = (nj << 4) + lr;
    gmax[nj] = fmaxf(fmaxf(red[0][c], red[1][c]), fmaxf(red[2][c], red[3][c]));
  }
  __syncthreads();

  // ---- prefetch first 4 mu ring slots; hide under exp pass ----
  const ushort* mbase = Atp + (size_t)wave * 32768 + lane * 8;
  short8 Mh[4];
#pragma unroll
  for (int i = 0; i < 4; ++i)
    Mh[i] = *(const short8*)(mbase + (size_t)i * 8192);

  float inv[2];
  {
    float ps[2] = {0.f, 0.f};
#pragma unroll
    for (int mi = 0; mi < 8; ++mi)
#pragma unroll
      for (int nj = 0; nj < 2; ++nj)
#pragma unroll
        for (int r = 0; r < 4; ++r) {
          float e = __expf(acc[mi][nj][r] - gmax[nj]);
          acc[mi][nj][r] = e;
          ps[nj] += e;
        }
#pragma unroll
    for (int nj = 0; nj < 2; ++nj) {
      ps[nj] += __shfl_xor(ps[nj], 16);
      ps[nj] += __shfl_xor(ps[nj], 32);
    }
    if (lg == 0) { red[wave][lr] = ps[0]; red[wave][16 + lr] = ps[1]; }
  }
  __syncthreads();
#pragma unroll
  for (int nj = 0; nj < 2; ++nj) {
    const int c = (nj << 4) + lr;
    inv[nj] = 1.0f / (red[0][c] + red[1][c] + red[2][c] + red[3][c]);
  }
  __syncthreads();   // red reads done; last Whi/Wlo reads were in s-loop

  // ---- alpha = exp*inv: fp32 to global, bf16 to LDS (PA aliases W),
  //      rowsum partials into rs_lds ----
  float ssq = 0.f;
#pragma unroll
  for (int mi = 0; mi < 8; ++mi) {
    const int tb = (wave << 7) + (mi << 4) + (lg << 2);
#pragma unroll
    for (int nj = 0; nj < 2; ++nj) {
#pragma unroll
      for (int r = 0; r < 4; ++r) acc[mi][nj][r] *= inv[nj];
      const int v = vb + (nj << 4) + lr;
      if (v < VOCAB) {
#pragma unroll
        for (int r = 0; r < 4; ++r)
          out_alpha[(size_t)(tb + r) * VOCAB + v] = acc[mi][nj][r];
      }
      uint2 pw;
      pw.x = packbf2(acc[mi][nj][0], acc[mi][nj][1]);
      pw.y = packbf2(acc[mi][nj][2], acc[mi][nj][3]);
      *(uint2*)&PA[(nj << 4) + lr][tb] = pw;
    }
    if (do_rl) {
#pragma unroll
      for (int r = 0; r < 4; ++r) {
        float rowp = 0.f;
#pragma unroll
        for (int nj = 0; nj < 2; ++nj) {
          float a = acc[mi][nj][r];
          float am = (vb + (nj << 4) + lr < VOCAB) ? a : 0.f;
          rowp += am;
          ssq = fmaf(am, am, ssq);
        }
        rowp += __shfl_xor(rowp, 1);
        rowp += __shfl_xor(rowp, 2);
        rowp += __shfl_xor(rowp, 4);
        rowp += __shfl_xor(rowp, 8);
        if (lr == 0) rs_lds[tb + r] = rowp;
      }
    }
  }
  __syncthreads();

  // ---- mu-GEMM: ring depth 4 steps, 2 MFMA/step ----
  f32x4 macc[4][2];
#pragma unroll
  for (int mi = 0; mi < 4; ++mi)
#pragma unroll
    for (int nj = 0; nj < 2; ++nj) macc[mi][nj] = (f32x4){0.f, 0.f, 0.f, 0.f};

#pragma unroll
  for (int ks = 0; ks < 16; ++ks) {
    const int k0 = (ks << 5) + (lg << 3);
    short8 pb[2];
#pragma unroll
    for (int nj = 0; nj < 2; ++nj)
      pb[nj] = *(const short8*)&PA[(nj << 4) + lr][k0];
#pragma unroll
    for (int mi = 0; mi < 4; ++mi) {
      const int n = (ks << 2) + mi;
      short8 ah = Mh[n & 3];
      if (n + 4 < 64) {
        const int n4 = n + 4;
        Mh[n & 3] = *(const short8*)(mbase + (size_t)(n4 & 3) * 8192
                                           + (size_t)(n4 >> 2) * 512);
      }
#pragma unroll
      for (int nj = 0; nj < 2; ++nj)
        macc[mi][nj] = __builtin_amdgcn_mfma_f32_16x16x32_bf16(ah, pb[nj], macc[mi][nj], 0, 0, 0);
    }
  }

  // ---- P: sum_d (w2v - mu)^2 per column (w2v re-read, L2-hot) ----
  {
    float pp[2] = {0.f, 0.f};
#pragma unroll
    for (int mi = 0; mi < 4; ++mi) {
      const int dbase = (wave << 6) + (mi << 4) + (lg << 2);
#pragma unroll
      for (int nj = 0; nj < 2; ++nj) {
        const int vr = min(vb + (nj << 4) + lr, VOCAB - 1);
        float4 w = *(const float4*)(w2v + (size_t)vr * 256 + dbase);
        float d0 = w.x - macc[mi][nj][0];
        float d1 = w.y - macc[mi][nj][1];
        float d2 = w.z - macc[mi][nj][2];
        float d3 = w.w - macc[mi][nj][3];
        pp[nj] += d0 * d0 + d1 * d1 + d2 * d2 + d3 * d3;
      }
    }
#pragma unroll
    for (int nj = 0; nj < 2; ++nj) {
      pp[nj] += __shfl_xor(pp[nj], 16);
      pp[nj] += __shfl_xor(pp[nj], 32);
    }
    if (lg == 0) { red[wave][lr] = pp[0]; red[wave][16 + lr] = pp[1]; }
  }
  __syncthreads();
  if (tid < VT) {
    float sum = red[0][tid] + red[1][tid] + red[2][tid] + red[3][tid];
    const int v = vb + tid;
    if (v < VOCAB) out_P[v] = sum / sigma[0];
  }

  // ---- coalesced part_rs block store (2KB contiguous) + ssq ----
  if (do_rl) {
    part_rs[(size_t)bid * TOPICS + tid]       = rs_lds[tid];
    part_rs[(size_t)bid * TOPICS + 256 + tid] = rs_lds[256 + tid];
    ssq += __shfl_xor(ssq, 1);
    ssq += __shfl_xor(ssq, 2);
    ssq += __shfl_xor(ssq, 4);
    ssq += __shfl_xor(ssq, 8);
    ssq += __shfl_xor(ssq, 16);
    ssq += __shfl_xor(ssq, 32);
    if (lane == 0) part_ss[bid * 4 + wave] = ssq;
  }
}

// ---------------------------------------------------------------------------
// RL pass 2: rowsum[t] = sum_blk part_rs[blk][t]. One block per topic.
// ---------------------------------------------------------------------------
__global__ __launch_bounds__(256) void rl_pass2(
    const float* __restrict__ part_rs, float* __restrict__ rowsum)
{
  const int t = blockIdx.x;
  float s = 0.f;
  for (int i = threadIdx.x; i < NBLK; i += 256)
    s += part_rs[(size_t)i * TOPICS + t];
  __shared__ float lsum[4];
  const int lane = threadIdx.x & 63, wave = threadIdx.x >> 6;
#pragma unroll
  for (int off = 32; off > 0; off >>= 1) s += __shfl_xor(s, off);
  if (lane == 0) lsum[wave] = s;
  __syncthreads();
  if (threadIdx.x == 0) rowsum[t] = lsum[0] + lsum[1] + lsum[2] + lsum[3];
}

__global__ __launch_bounds__(512) void rl_final_new(
    const float* __restrict__ rowsum, const float* __restrict__ part_ss,
    const float* __restrict__ sigma, float* __restrict__ out_RL,
    float* __restrict__ out_sigma)
{
  const int t = threadIdx.x;
  float b = rowsum[t] * rowsum[t];
  float a = 0.f;
  for (int i = t; i < NBLK * 4; i += 512) a += part_ss[i];
  __shared__ float la[8], lb[8];
  const int lane = t & 63, wave = t >> 6;
#pragma unroll
  for (int off = 32; off > 0; off >>= 1) {
    a += __shfl_xor(a, off);
    b += __shfl_xor(b, off);
  }
  if (lane == 0) { la[wave] = a; lb[wave] = b; }
  __syncthreads();
  if (t == 0) {
    float sa = 0.f, sb = 0.f;
#pragma unroll
    for (int w = 0; w < 8; ++w) { sa += la[w]; sb += lb[w]; }
    out_RL[0] = sa - sb / (float)VOCAB;
    out_sigma[0] = sigma[0];
  }
}

// ---------------------------------------------------------------------------
// Fallback (small ws): alpha re-read path
// ---------------------------------------------------------------------------
__global__ __launch_bounds__(256) void row_reduce(
    const float* __restrict__ alpha, float* __restrict__ rowsum, float* __restrict__ ssum)
{
  const int t = blockIdx.x;
  const float4* base = (const float4*)(alpha + (size_t)t * VOCAB);
  float rs = 0.f, ss = 0.f;
  for (int i = threadIdx.x; i < VOCAB / 4; i += 256) {
    float4 a = base[i];
    rs += a.x + a.y + a.z + a.w;
    ss += a.x * a.x + a.y * a.y + a.z * a.z + a.w * a.w;
  }
  __shared__ float lr[4], ls[4];
  const int lane = threadIdx.x & 63, wave = threadIdx.x >> 6;
#pragma unroll
  for (int off = 32; off > 0; off >>= 1) {
    rs += __shfl_xor(rs, off);
    ss += __shfl_xor(ss, off);
  }
  if (lane == 0) { lr[wave] = rs; ls[wave] = ss; }
  __syncthreads();
  if (threadIdx.x == 0) {
    rowsum[t] = lr[0] + lr[1] + lr[2] + lr[3];
    ssum[t]   = ls[0] + ls[1] + ls[2] + ls[3];
  }
}

__global__ __launch_bounds__(512) void rl_final_old(
    const float* __restrict__ rowsum, const float* __restrict__ ssum,
    const float* __restrict__ sigma, float* __restrict__ out_RL,
    float* __restrict__ out_sigma)
{
  const int t = threadIdx.x;
  float a = ssum[t];
  float b = rowsum[t] * rowsum[t];
  __shared__ float la[8], lb[8];
  const int lane = t & 63, wave = t >> 6;
#pragma unroll
  for (int off = 32; off > 0; off >>= 1) {
    a += __shfl_xor(a, off);
    b += __shfl_xor(b, off);
  }
  if (lane == 0) { la[wave] = a; lb[wave] = b; }
  __syncthreads();
  if (t == 0) {
    float sa = 0.f, sb = 0.f;
#pragma unroll
    for (int w = 0; w < 8; ++w) { sa += la[w]; sb += lb[w]; }
    out_RL[0] = sa - sb / (float)VOCAB;
    out_sigma[0] = sigma[0];
  }
}

extern "C" void kernel_launch(void* const* d_in, const int* in_sizes, int n_in,
                              void* d_out, int out_size, void* d_ws, size_t ws_size,
                              hipStream_t stream) {
  const float* w2v   = (const float*)d_in[0];  // [50000][256]
  const float* t2v   = (const float*)d_in[1];  // [512][256]
  const float* A     = (const float*)d_in[2];  // [256][256]
  const float* B     = (const float*)d_in[3];  // [256][256]
  const float* sigma = (const float*)d_in[4];  // [1]

  float* out       = (float*)d_out;
  float* out_alpha = out;                                  // 25,600,000
  float* out_P     = out + (size_t)TOPICS * VOCAB;         // 50,000
  float* out_RL    = out_P + VOCAB;                        // 1
  float* out_s     = out_RL + 1;                           // 25,600,000
  float* out_sigma = out_s + (size_t)TOPICS * VOCAB;       // 1

  ushort* tBp = (ushort*)d_ws;                             // 131072 ushorts (256 KB)
  ushort* Atp = tBp + (size_t)131072;                      // 131072 ushorts (256 KB)
  float* tail = (float*)(Atp + (size_t)131072);
  float* part_rs = tail;                                   // [NBLK][512]
  float* part_ss = part_rs + (size_t)NBLK * TOPICS;        // 1563*4
  float* rowsum  = part_ss + (size_t)NBLK * 4;             // 512
  size_t need = (size_t)(2 * 131072) * 2 +
                ((size_t)NBLK * TOPICS + (size_t)NBLK * 4 + TOPICS) * 4;
  const int do_rl = (ws_size >= need) ? 1 : 0;

  precompute<<<TOPICS + VDIM, 512, 0, stream>>>(t2v, A, B, tBp, Atp);

  fused_main<<<NBLK, 256, 0, stream>>>(w2v, tBp, Atp, sigma,
                                       out_alpha, out_P, out_s,
                                       part_rs, part_ss, do_rl);

  if (do_rl) {
    rl_pass2<<<TOPICS, 256, 0, stream>>>(part_rs, rowsum);
    rl_final_new<<<1, 512, 0, stream>>>(rowsum, part_ss, sigma, out_RL, out_sigma);
  } else {
    float* rs_old = tail;
    float* ss_old = rs_old + TOPICS;
    row_reduce<<<TOPICS, 256, 0, stream>>>(out_alpha, rs_old, ss_old);
    rl_final_old<<<1, 512, 0, stream>>>(rs_old, ss_old, sigma, out_RL, out_sigma);
  }
}

// Round 15
// 152.484 us; speedup vs baseline: 1.2849x; 1.1124x over previous
//
#include <hip/hip_runtime.h>

#define VOCAB 50000
#define VDIM 256
#define TOPICS 512
#define VT 32
#define NBLK 1563   // ceil(VOCAB/VT)
#define NXCD 8

typedef unsigned int uint;
typedef unsigned short ushort;
using short8 = __attribute__((ext_vector_type(8))) short;
using f32x4  = __attribute__((ext_vector_type(4))) float;

__device__ __forceinline__ ushort bf16_rne(float f) {
  uint u = __float_as_uint(f);
  u += 0x7FFFu + ((u >> 16) & 1u);
  return (ushort)(u >> 16);
}
__device__ __forceinline__ float bf16f(ushort h) {
  return __uint_as_float(((uint)h) << 16);
}
__device__ __forceinline__ uint packbf2(float a, float b) {
  return (uint)bf16_rne(a) | ((uint)bf16_rne(b) << 16);
}

// Bijective chunked XCD swizzle (m204): consecutive logical ids -> same XCD.
__device__ __forceinline__ int xcd_swizzle(int orig, int nwg) {
  const int q = nwg / NXCD, r = nwg % NXCD;
  const int xcd = orig % NXCD, i = orig / NXCD;
  return (xcd < r ? xcd * (q + 1) : r * (q + 1) + (xcd - r) * q) + i;
}

// ---------------------------------------------------------------------------
// Precompute, single-plane bf16 fragment-major packing:
//   tBp[tile=t>>4][ks=d>>5][lane=(t&15)|(((d>>3)&3)<<4)][e=d&7]   (256 KB)
//   Atp[dtile=d>>4][ks=t>>5][lane=(d&15)|(((t>>3)&3)<<4)][e=t&7]  (256 KB)
// ---------------------------------------------------------------------------
__global__ __launch_bounds__(512) void precompute(
    const float* __restrict__ t2v, const float* __restrict__ A,
    const float* __restrict__ B,
    ushort* __restrict__ tBp, ushort* __restrict__ Atp)
{
  __shared__ float row[256];
  const int b = blockIdx.x, tid = threadIdx.x;
  if (b < TOPICS) {
    const int t = b;
    if (tid < 256) row[tid] = t2v[(size_t)t * 256 + tid];
    __syncthreads();
    if (tid < 256) {
      const int d = tid;
      const float4* rv = (const float4*)row;
      const float4* bv = (const float4*)(B + (size_t)d * 256);
      float acc = 0.f;
#pragma unroll 8
      for (int k = 0; k < 64; ++k) {
        float4 r = rv[k], x = bv[k];
        acc += r.x * x.x + r.y * x.y + r.z * x.z + r.w * x.w;
      }
      const int tile = t >> 4, ks = d >> 5;
      const int lane = (t & 15) | (((d >> 3) & 3) << 4);
      const int e = d & 7;
      tBp[((size_t)tile * 8 + ks) * 512 + lane * 8 + e] = bf16_rne(acc);
    }
  } else {
    const int d = b - TOPICS;
    if (tid < 256) row[tid] = A[(size_t)d * 256 + tid];
    __syncthreads();
    const int t = tid;
    const float4* rv = (const float4*)row;
    const float4* tv = (const float4*)(t2v + (size_t)t * 256);
    float acc = 0.f;
#pragma unroll 8
    for (int k = 0; k < 64; ++k) {
      float4 r = rv[k], x = tv[k];
      acc += r.x * x.x + r.y * x.y + r.z * x.z + r.w * x.w;
    }
    const int dtile = d >> 4, ks = t >> 5;
    const int lane = (d & 15) | (((t >> 3) & 3) << 4);
    const int e = t & 7;
    Atp[((size_t)dtile * 16 + ks) * 512 + lane * 8 + e] = bf16_rne(acc);
  }
}

// ---------------------------------------------------------------------------
// Fused main — R14 structure; NEW: s and alpha stores vectorized via a
// swizzled LDS transpose tile (SST reuses the dead W region). Each store
// instruction now writes 8 full 128B contiguous row-spans (float4/lane).
// ---------------------------------------------------------------------------
__global__ __launch_bounds__(256, 4) void fused_main(
    const float* __restrict__ w2v,
    const ushort* __restrict__ tBp, const ushort* __restrict__ Atp,
    const float* __restrict__ sigma,
    float* __restrict__ out_alpha, float* __restrict__ out_P,
    float* __restrict__ out_s,
    float* __restrict__ part_rs, float* __restrict__ part_ss, int do_rl)
{
  __shared__ __align__(16) char smem[33792];
  ushort (*Whi)[264] = (ushort (*)[264])smem;            // 16896 B
  ushort (*Wlo)[264] = (ushort (*)[264])(smem + 16896);  // 16896 B
  ushort (*PA)[520]  = (ushort (*)[520])smem;            // 33280 B (alias, W dead)
  float  (*SST)[32]  = (float  (*)[32])smem;             // 32768 B (alias, stage)
  __shared__ float red[4][VT];
  __shared__ float rs_lds[TOPICS];

  const int tid  = threadIdx.x;
  const int wave = tid >> 6, lane = tid & 63;
  const int lr = lane & 15, lg = lane >> 4;
  const int bid = xcd_swizzle(blockIdx.x, NBLK);
  const int vb = bid * VT;

  // ---- prefetch first 4 ring slots (steps 0..3) ----
  const ushort* sbase = tBp + (size_t)wave * 32768 + lane * 8;
  short8 Ah[4];
#pragma unroll
  for (int i = 0; i < 4; ++i)
    Ah[i] = *(const short8*)(sbase + (size_t)i * 4096);

  // ---- stage W hi/lo ----
#pragma unroll
  for (int it = 0; it < 8; ++it) {
    int j = tid + (it << 8);
    int v = j >> 6, q = j & 63;
    int vr = min(vb + v, VOCAB - 1);
    float4 x = *(const float4*)(w2v + (size_t)vr * 256 + (q << 2));
    float xs[4] = {x.x, x.y, x.z, x.w};
    ushort h[4], l[4];
#pragma unroll
    for (int i = 0; i < 4; ++i) {
      ushort hi = bf16_rne(xs[i]);
      h[i] = hi;
      l[i] = bf16_rne(xs[i] - bf16f(hi));
    }
    *(uint2*)&Whi[v][q << 2] = make_uint2((uint)h[0] | ((uint)h[1] << 16),
                                          (uint)h[2] | ((uint)h[3] << 16));
    *(uint2*)&Wlo[v][q << 2] = make_uint2((uint)l[0] | ((uint)l[1] << 16),
                                          (uint)l[2] | ((uint)l[3] << 16));
  }
  __syncthreads();

  // ---- s-GEMM: ring depth 4 steps, 4 MFMA/step ----
  f32x4 acc[8][2];
#pragma unroll
  for (int mi = 0; mi < 8; ++mi)
#pragma unroll
    for (int nj = 0; nj < 2; ++nj) acc[mi][nj] = (f32x4){0.f, 0.f, 0.f, 0.f};

#pragma unroll
  for (int ks = 0; ks < 8; ++ks) {
    const int k0 = (ks << 5) + (lg << 3);
    short8 bh[2], bl[2];
#pragma unroll
    for (int nj = 0; nj < 2; ++nj) {
      bh[nj] = *(const short8*)&Whi[(nj << 4) + lr][k0];
      bl[nj] = *(const short8*)&Wlo[(nj << 4) + lr][k0];
    }
#pragma unroll
    for (int mi = 0; mi < 8; ++mi) {
      const int n = (ks << 3) + mi;
      short8 ah = Ah[n & 3];
      if (n + 4 < 64) {
        const int n4 = n + 4;
        Ah[n & 3] = *(const short8*)(sbase + (size_t)(n4 & 7) * 4096
                                           + (size_t)(n4 >> 3) * 512);
      }
#pragma unroll
      for (int nj = 0; nj < 2; ++nj) {
        acc[mi][nj] = __builtin_amdgcn_mfma_f32_16x16x32_bf16(ah, bh[nj], acc[mi][nj], 0, 0, 0);
        acc[mi][nj] = __builtin_amdgcn_mfma_f32_16x16x32_bf16(ah, bl[nj], acc[mi][nj], 0, 0, 0);
      }
    }
  }
  __syncthreads();   // all waves done reading W; SST may overwrite it

  // ---- s store, vectorized: 2 phases of 256 rows each ----
#pragma unroll
  for (int ph = 0; ph < 2; ++ph) {
    if ((wave >> 1) == ph) {     // waves {0,1} stage phase 0; {2,3} phase 1
#pragma unroll
      for (int mi = 0; mi < 8; ++mi) {
        const int tb = ((wave & 1) << 7) + (mi << 4) + (lg << 2);
#pragma unroll
        for (int r = 0; r < 4; ++r) {
          const int t = tb + r, sw = (t & 7) << 2;
#pragma unroll
          for (int nj = 0; nj < 2; ++nj)
            SST[t][((nj << 4) + lr) ^ sw] = acc[mi][nj][r];
        }
      }
    }
    __syncthreads();
    {
      const int row = tid >> 3, cb = (tid & 7) << 2;
      const int v = vb + cb;
#pragma unroll
      for (int it = 0; it < 8; ++it) {
        const int t = row + (it << 5);
        if (v < VOCAB)
          *(float4*)(out_s + (size_t)(t + (ph << 8)) * VOCAB + v) =
              *(const float4*)&SST[t][cb ^ ((t & 7) << 2)];
      }
    }
    __syncthreads();
  }

  // ---- softmax max ----
  float gmax[2];
  {
    float pm[2] = {-3.4e38f, -3.4e38f};
#pragma unroll
    for (int mi = 0; mi < 8; ++mi)
#pragma unroll
      for (int nj = 0; nj < 2; ++nj)
#pragma unroll
        for (int r = 0; r < 4; ++r) pm[nj] = fmaxf(pm[nj], acc[mi][nj][r]);
#pragma unroll
    for (int nj = 0; nj < 2; ++nj) {
      pm[nj] = fmaxf(pm[nj], __shfl_xor(pm[nj], 16));
      pm[nj] = fmaxf(pm[nj], __shfl_xor(pm[nj], 32));
    }
    if (lg == 0) { red[wave][lr] = pm[0]; red[wave][16 + lr] = pm[1]; }
  }
  __syncthreads();
#pragma unroll
  for (int nj = 0; nj < 2; ++nj) {
    const int c = (nj << 4) + lr;
    gmax[nj] = fmaxf(fmaxf(red[0][c], red[1][c]), fmaxf(red[2][c], red[3][c]));
  }
  __syncthreads();

  // ---- prefetch first 4 mu ring slots; hide under exp pass ----
  const ushort* mbase = Atp + (size_t)wave * 32768 + lane * 8;
  short8 Mh[4];
#pragma unroll
  for (int i = 0; i < 4; ++i)
    Mh[i] = *(const short8*)(mbase + (size_t)i * 8192);

  float inv[2];
  {
    float ps[2] = {0.f, 0.f};
#pragma unroll
    for (int mi = 0; mi < 8; ++mi)
#pragma unroll
      for (int nj = 0; nj < 2; ++nj)
#pragma unroll
        for (int r = 0; r < 4; ++r) {
          float e = __expf(acc[mi][nj][r] - gmax[nj]);
          acc[mi][nj][r] = e;
          ps[nj] += e;
        }
#pragma unroll
    for (int nj = 0; nj < 2; ++nj) {
      ps[nj] += __shfl_xor(ps[nj], 16);
      ps[nj] += __shfl_xor(ps[nj], 32);
    }
    if (lg == 0) { red[wave][lr] = ps[0]; red[wave][16 + lr] = ps[1]; }
  }
  __syncthreads();
#pragma unroll
  for (int nj = 0; nj < 2; ++nj) {
    const int c = (nj << 4) + lr;
    inv[nj] = 1.0f / (red[0][c] + red[1][c] + red[2][c] + red[3][c]);
  }
  __syncthreads();

  // ---- scale acc -> alpha (registers) ----
#pragma unroll
  for (int mi = 0; mi < 8; ++mi)
#pragma unroll
    for (int nj = 0; nj < 2; ++nj)
#pragma unroll
      for (int r = 0; r < 4; ++r) acc[mi][nj][r] *= inv[nj];

  // ---- alpha store, vectorized (same 2-phase staging; rows 128B-aligned) ----
#pragma unroll
  for (int ph = 0; ph < 2; ++ph) {
    if ((wave >> 1) == ph) {
#pragma unroll
      for (int mi = 0; mi < 8; ++mi) {
        const int tb = ((wave & 1) << 7) + (mi << 4) + (lg << 2);
#pragma unroll
        for (int r = 0; r < 4; ++r) {
          const int t = tb + r, sw = (t & 7) << 2;
#pragma unroll
          for (int nj = 0; nj < 2; ++nj)
            SST[t][((nj << 4) + lr) ^ sw] = acc[mi][nj][r];
        }
      }
    }
    __syncthreads();
    {
      const int row = tid >> 3, cb = (tid & 7) << 2;
      const int v = vb + cb;
#pragma unroll
      for (int it = 0; it < 8; ++it) {
        const int t = row + (it << 5);
        if (v < VOCAB)
          *(float4*)(out_alpha + (size_t)(t + (ph << 8)) * VOCAB + v) =
              *(const float4*)&SST[t][cb ^ ((t & 7) << 2)];
      }
    }
    __syncthreads();
  }

  // ---- PA bf16 (overwrites SST region) + RL partials ----
  float ssq = 0.f;
#pragma unroll
  for (int mi = 0; mi < 8; ++mi) {
    const int tb = (wave << 7) + (mi << 4) + (lg << 2);
#pragma unroll
    for (int nj = 0; nj < 2; ++nj) {
      uint2 pw;
      pw.x = packbf2(acc[mi][nj][0], acc[mi][nj][1]);
      pw.y = packbf2(acc[mi][nj][2], acc[mi][nj][3]);
      *(uint2*)&PA[(nj << 4) + lr][tb] = pw;
    }
    if (do_rl) {
#pragma unroll
      for (int r = 0; r < 4; ++r) {
        float rowp = 0.f;
#pragma unroll
        for (int nj = 0; nj < 2; ++nj) {
          float a = acc[mi][nj][r];
          float am = (vb + (nj << 4) + lr < VOCAB) ? a : 0.f;
          rowp += am;
          ssq = fmaf(am, am, ssq);
        }
        rowp += __shfl_xor(rowp, 1);
        rowp += __shfl_xor(rowp, 2);
        rowp += __shfl_xor(rowp, 4);
        rowp += __shfl_xor(rowp, 8);
        if (lr == 0) rs_lds[tb + r] = rowp;
      }
    }
  }
  __syncthreads();

  // ---- mu-GEMM: ring depth 4 steps, 2 MFMA/step ----
  f32x4 macc[4][2];
#pragma unroll
  for (int mi = 0; mi < 4; ++mi)
#pragma unroll
    for (int nj = 0; nj < 2; ++nj) macc[mi][nj] = (f32x4){0.f, 0.f, 0.f, 0.f};

#pragma unroll
  for (int ks = 0; ks < 16; ++ks) {
    const int k0 = (ks << 5) + (lg << 3);
    short8 pb[2];
#pragma unroll
    for (int nj = 0; nj < 2; ++nj)
      pb[nj] = *(const short8*)&PA[(nj << 4) + lr][k0];
#pragma unroll
    for (int mi = 0; mi < 4; ++mi) {
      const int n = (ks << 2) + mi;
      short8 ah = Mh[n & 3];
      if (n + 4 < 64) {
        const int n4 = n + 4;
        Mh[n & 3] = *(const short8*)(mbase + (size_t)(n4 & 3) * 8192
                                           + (size_t)(n4 >> 2) * 512);
      }
#pragma unroll
      for (int nj = 0; nj < 2; ++nj)
        macc[mi][nj] = __builtin_amdgcn_mfma_f32_16x16x32_bf16(ah, pb[nj], macc[mi][nj], 0, 0, 0);
    }
  }

  // ---- P: sum_d (w2v - mu)^2 per column (w2v re-read, L2/L3) ----
  {
    float pp[2] = {0.f, 0.f};
#pragma unroll
    for (int mi = 0; mi < 4; ++mi) {
      const int dbase = (wave << 6) + (mi << 4) + (lg << 2);
#pragma unroll
      for (int nj = 0; nj < 2; ++nj) {
        const int vr = min(vb + (nj << 4) + lr, VOCAB - 1);
        float4 w = *(const float4*)(w2v + (size_t)vr * 256 + dbase);
        float d0 = w.x - macc[mi][nj][0];
        float d1 = w.y - macc[mi][nj][1];
        float d2 = w.z - macc[mi][nj][2];
        float d3 = w.w - macc[mi][nj][3];
        pp[nj] += d0 * d0 + d1 * d1 + d2 * d2 + d3 * d3;
      }
    }
#pragma unroll
    for (int nj = 0; nj < 2; ++nj) {
      pp[nj] += __shfl_xor(pp[nj], 16);
      pp[nj] += __shfl_xor(pp[nj], 32);
    }
    if (lg == 0) { red[wave][lr] = pp[0]; red[wave][16 + lr] = pp[1]; }
  }
  __syncthreads();
  if (tid < VT) {
    float sum = red[0][tid] + red[1][tid] + red[2][tid] + red[3][tid];
    const int v = vb + tid;
    if (v < VOCAB) out_P[v] = sum / sigma[0];
  }

  // ---- coalesced part_rs block store (2KB contiguous) + ssq ----
  if (do_rl) {
    part_rs[(size_t)bid * TOPICS + tid]       = rs_lds[tid];
    part_rs[(size_t)bid * TOPICS + 256 + tid] = rs_lds[256 + tid];
    ssq += __shfl_xor(ssq, 1);
    ssq += __shfl_xor(ssq, 2);
    ssq += __shfl_xor(ssq, 4);
    ssq += __shfl_xor(ssq, 8);
    ssq += __shfl_xor(ssq, 16);
    ssq += __shfl_xor(ssq, 32);
    if (lane == 0) part_ss[bid * 4 + wave] = ssq;
  }
}

// ---------------------------------------------------------------------------
// RL pass 2: rowsum[t] = sum_blk part_rs[blk][t]. One block per topic.
// ---------------------------------------------------------------------------
__global__ __launch_bounds__(256) void rl_pass2(
    const float* __restrict__ part_rs, float* __restrict__ rowsum)
{
  const int t = blockIdx.x;
  float s = 0.f;
  for (int i = threadIdx.x; i < NBLK; i += 256)
    s += part_rs[(size_t)i * TOPICS + t];
  __shared__ float lsum[4];
  const int lane = threadIdx.x & 63, wave = threadIdx.x >> 6;
#pragma unroll
  for (int off = 32; off > 0; off >>= 1) s += __shfl_xor(s, off);
  if (lane == 0) lsum[wave] = s;
  __syncthreads();
  if (threadIdx.x == 0) rowsum[t] = lsum[0] + lsum[1] + lsum[2] + lsum[3];
}

__global__ __launch_bounds__(512) void rl_final_new(
    const float* __restrict__ rowsum, const float* __restrict__ part_ss,
    const float* __restrict__ sigma, float* __restrict__ out_RL,
    float* __restrict__ out_sigma)
{
  const int t = threadIdx.x;
  float b = rowsum[t] * rowsum[t];
  float a = 0.f;
  for (int i = t; i < NBLK * 4; i += 512) a += part_ss[i];
  __shared__ float la[8], lb[8];
  const int lane = t & 63, wave = t >> 6;
#pragma unroll
  for (int off = 32; off > 0; off >>= 1) {
    a += __shfl_xor(a, off);
    b += __shfl_xor(b, off);
  }
  if (lane == 0) { la[wave] = a; lb[wave] = b; }
  __syncthreads();
  if (t == 0) {
    float sa = 0.f, sb = 0.f;
#pragma unroll
    for (int w = 0; w < 8; ++w) { sa += la[w]; sb += lb[w]; }
    out_RL[0] = sa - sb / (float)VOCAB;
    out_sigma[0] = sigma[0];
  }
}

// ---------------------------------------------------------------------------
// Fallback (small ws): alpha re-read path
// ---------------------------------------------------------------------------
__global__ __launch_bounds__(256) void row_reduce(
    const float* __restrict__ alpha, float* __restrict__ rowsum, float* __restrict__ ssum)
{
  const int t = blockIdx.x;
  const float4* base = (const float4*)(alpha + (size_t)t * VOCAB);
  float rs = 0.f, ss = 0.f;
  for (int i = threadIdx.x; i < VOCAB / 4; i += 256) {
    float4 a = base[i];
    rs += a.x + a.y + a.z + a.w;
    ss += a.x * a.x + a.y * a.y + a.z * a.z + a.w * a.w;
  }
  __shared__ float lr[4], ls[4];
  const int lane = threadIdx.x & 63, wave = threadIdx.x >> 6;
#pragma unroll
  for (int off = 32; off > 0; off >>= 1) {
    rs += __shfl_xor(rs, off);
    ss += __shfl_xor(ss, off);
  }
  if (lane == 0) { lr[wave] = rs; ls[wave] = ss; }
  __syncthreads();
  if (threadIdx.x == 0) {
    rowsum[t] = lr[0] + lr[1] + lr[2] + lr[3];
    ssum[t]   = ls[0] + ls[1] + ls[2] + ls[3];
  }
}

__global__ __launch_bounds__(512) void rl_final_old(
    const float* __restrict__ rowsum, const float* __restrict__ ssum,
    const float* __restrict__ sigma, float* __restrict__ out_RL,
    float* __restrict__ out_sigma)
{
  const int t = threadIdx.x;
  float a = ssum[t];
  float b = rowsum[t] * rowsum[t];
  __shared__ float la[8], lb[8];
  const int lane = t & 63, wave = t >> 6;
#pragma unroll
  for (int off = 32; off > 0; off >>= 1) {
    a += __shfl_xor(a, off);
    b += __shfl_xor(b, off);
  }
  if (lane == 0) { la[wave] = a; lb[wave] = b; }
  __syncthreads();
  if (t == 0) {
    float sa = 0.f, sb = 0.f;
#pragma unroll
    for (int w = 0; w < 8; ++w) { sa += la[w]; sb += lb[w]; }
    out_RL[0] = sa - sb / (float)VOCAB;
    out_sigma[0] = sigma[0];
  }
}

extern "C" void kernel_launch(void* const* d_in, const int* in_sizes, int n_in,
                              void* d_out, int out_size, void* d_ws, size_t ws_size,
                              hipStream_t stream) {
  const float* w2v   = (const float*)d_in[0];  // [50000][256]
  const float* t2v   = (const float*)d_in[1];  // [512][256]
  const float* A     = (const float*)d_in[2];  // [256][256]
  const float* B     = (const float*)d_in[3];  // [256][256]
  const float* sigma = (const float*)d_in[4];  // [1]

  float* out       = (float*)d_out;
  float* out_alpha = out;                                  // 25,600,000
  float* out_P     = out + (size_t)TOPICS * VOCAB;         // 50,000
  float* out_RL    = out_P + VOCAB;                        // 1
  float* out_s     = out_RL + 1;                           // 25,600,000
  float* out_sigma = out_s + (size_t)TOPICS * VOCAB;       // 1

  ushort* tBp = (ushort*)d_ws;                             // 131072 ushorts (256 KB)
  ushort* Atp = tBp + (size_t)131072;                      // 131072 ushorts (256 KB)
  float* tail = (float*)(Atp + (size_t)131072);
  float* part_rs = tail;                                   // [NBLK][512]
  float* part_ss = part_rs + (size_t)NBLK * TOPICS;        // 1563*4
  float* rowsum  = part_ss + (size_t)NBLK * 4;             // 512
  size_t need = (size_t)(2 * 131072) * 2 +
                ((size_t)NBLK * TOPICS + (size_t)NBLK * 4 + TOPICS) * 4;
  const int do_rl = (ws_size >= need) ? 1 : 0;

  precompute<<<TOPICS + VDIM, 512, 0, stream>>>(t2v, A, B, tBp, Atp);

  fused_main<<<NBLK, 256, 0, stream>>>(w2v, tBp, Atp, sigma,
                                       out_alpha, out_P, out_s,
                                       part_rs, part_ss, do_rl);

  if (do_rl) {
    rl_pass2<<<TOPICS, 256, 0, stream>>>(part_rs, rowsum);
    rl_final_new<<<1, 512, 0, stream>>>(rowsum, part_ss, sigma, out_RL, out_sigma);
  } else {
    float* rs_old = tail;
    float* ss_old = rs_old + TOPICS;
    row_reduce<<<TOPICS, 256, 0, stream>>>(out_alpha, rs_old, ss_old);
    rl_final_old<<<1, 512, 0, stream>>>(rs_old, ss_old, sigma, out_RL, out_sigma);
  }
}